// Round 11
// baseline (220.783 us; speedup 1.0000x reference)
//
#include <hip/hip_runtime.h>
#include <hip/hip_fp16.h>

#define IN_F 128
#define H_F 64
#define C_F 16
#define BUCKET 64           // nodes per bucket
#define BSH 6               // log2(BUCKET)
#define MAXB 2048           // hist/scan capacity (>= nBuckets = ceil(N/64))
#define EPB 8192            // edges per k_bhist block
#define EPB2 32768          // edges per k_bin block (long runs -> low write amplification)
#define CAP 2048            // staged codes per k_agg block
#define NRED 64             // stage-1 reduction blocks

// ---------------- fused bucket histograms (src + dst), no per-node atomics ----------
__global__ __launch_bounds__(256) void k_bhist(const int* __restrict__ src,
                                               const int* __restrict__ dst,
                                               int* __restrict__ cntS,
                                               int* __restrict__ cntD, int E, int nb) {
    __shared__ int hs[MAXB];
    __shared__ int hd[MAXB];
    const int tid = threadIdx.x;
    for (int i = tid; i < MAXB; i += 256) { hs[i] = 0; hd[i] = 0; }
    __syncthreads();
    const int start = blockIdx.x * EPB;
    for (int k = 0; k < EPB / 256; ++k) {
        int e = start + (k << 8) + tid;
        if (e < E) {
            atomicAdd(&hs[src[e] >> BSH], 1);
            atomicAdd(&hd[dst[e] >> BSH], 1);
        }
    }
    __syncthreads();
    for (int b = tid; b < nb; b += 256) {
        int s = hs[b], d = hd[b];
        if (s) atomicAdd(&cntS[b], s);
        if (d) atomicAdd(&cntD[b], d);
    }
}

// ------------- exclusive scans of BOTH bucket-count arrays (single block) -------------
__global__ __launch_bounds__(1024) void k_bucketscan2(const int* __restrict__ cntD,
                                                      const int* __restrict__ cntS,
                                                      int* __restrict__ baseD,
                                                      int* __restrict__ curD,
                                                      int* __restrict__ baseS,
                                                      int* __restrict__ curS,
                                                      int nb, int E) {
    __shared__ int s[1024];
    const int t = threadIdx.x;
    for (int pass = 0; pass < 2; ++pass) {
        const int* cnt = pass ? cntS : cntD;
        int* base = pass ? baseS : baseD;
        int* cur  = pass ? curS  : curD;
        int i0 = 2 * t, i1 = 2 * t + 1;
        int v0 = (i0 < nb) ? cnt[i0] : 0;
        int v1 = (i1 < nb) ? cnt[i1] : 0;
        int pair = v0 + v1;
        s[t] = pair;
        __syncthreads();
        for (int off = 1; off < 1024; off <<= 1) {
            int x = (t >= off) ? s[t - off] : 0;
            __syncthreads();
            s[t] += x;
            __syncthreads();
        }
        int excl = s[t] - pair;
        if (i0 < nb) { base[i0] = excl;      cur[i0] = excl; }
        if (i1 < nb) { base[i1] = excl + v0; cur[i1] = excl + v0; }
        if (t == 0) base[nb] = E;
        __syncthreads();
    }
}

// ------------- role-split binning: blocks [0,nBinW) bin by dst, [nBinW,2*nBinW) by src
// code = (klocal << 17) | payload
__global__ __launch_bounds__(512) void k_bin(const int* __restrict__ src,
                                             const int* __restrict__ dst,
                                             int* __restrict__ gCurD,
                                             int* __restrict__ gCurS,
                                             unsigned int* __restrict__ binnedD,
                                             unsigned int* __restrict__ binnedS,
                                             int E, int nb, int nBinW) {
    __shared__ int hist[MAXB];
    __shared__ int base[MAXB];
    __shared__ int cur[MAXB];
    const int tid = threadIdx.x;
    const bool roleS = (int)blockIdx.x >= nBinW;
    const int blk = roleS ? (int)blockIdx.x - nBinW : (int)blockIdx.x;
    const int* __restrict__ key = roleS ? src : dst;
    const int* __restrict__ pay = roleS ? dst : src;
    int* gCur = roleS ? gCurS : gCurD;
    unsigned int* out = roleS ? binnedS : binnedD;
    const int start = blk * EPB2;

    for (int i = tid; i < MAXB; i += 512) { hist[i] = 0; cur[i] = 0; }
    __syncthreads();
    for (int k = 0; k < EPB2 / 512; ++k) {
        int e = start + (k << 9) + tid;
        if (e < E) atomicAdd(&hist[key[e] >> BSH], 1);
    }
    __syncthreads();
    for (int b = tid; b < nb; b += 512)
        if (hist[b]) base[b] = atomicAdd(&gCur[b], hist[b]);
    __syncthreads();
    for (int k = 0; k < EPB2 / 512; ++k) {
        int e = start + (k << 9) + tid;
        if (e < E) {
            int kv = key[e];
            int b = kv >> BSH;
            int p = base[b] + atomicAdd(&cur[b], 1);
            out[p] = ((unsigned)(kv & (BUCKET - 1)) << 17) | (unsigned)pay[e];
        }
    }
}

// ---------------- norm_in from binnedD (per dst-bucket 64-bin histogram) ----------------
__global__ __launch_bounds__(256) void k_normin(const unsigned int* __restrict__ binnedD,
                                                const int* __restrict__ baseD,
                                                float* __restrict__ norm_in, int N) {
    __shared__ int hist[BUCKET];
    const int tid = threadIdx.x;
    if (tid < BUCKET) hist[tid] = 0;
    __syncthreads();
    const int b = blockIdx.x;
    const int s0 = baseD[b], s1 = baseD[b + 1];
    for (int i = s0 + tid; i < s1; i += 256)
        atomicAdd(&hist[binnedD[i] >> 17], 1);
    __syncthreads();
    if (tid < BUCKET) {
        int gn = b * BUCKET + tid;
        if (gn < N) norm_in[gn] = 1.0f / sqrtf((float)max(hist[tid], 1));
    }
}

// ---------------- wsum + norm_out from binnedS (per src-bucket) ----------------
__global__ __launch_bounds__(256) void k_wsum(const unsigned int* __restrict__ binnedS,
                                              const int* __restrict__ baseS,
                                              const float* __restrict__ norm_in,
                                              float* __restrict__ wsum,
                                              float* __restrict__ norm_out, int N) {
    __shared__ float wloc[BUCKET];
    __shared__ int hist[BUCKET];
    const int tid = threadIdx.x;
    if (tid < BUCKET) { wloc[tid] = 0.0f; hist[tid] = 0; }
    __syncthreads();
    const int b = blockIdx.x;
    const int s0 = baseS[b], s1 = baseS[b + 1];
    for (int i = s0 + tid; i < s1; i += 256) {
        unsigned c = binnedS[i];
        int sl = (int)(c >> 17);
        float ni = norm_in[c & 0x1FFFFu];
        atomicAdd(&hist[sl], 1);
        atomicAdd(&wloc[sl], ni);
    }
    __syncthreads();
    if (tid < BUCKET) {
        int gn = b * BUCKET + tid;
        if (gn < N) {
            norm_out[gn] = 1.0f / sqrtf((float)max(hist[tid], 1));
            wsum[gn] = wloc[tid];
        }
    }
}

// ------- layer 1 GEMM: X1q = fp8_e4m3((in_feat @ W1) * norm_out), [N,64] bytes -------
__global__ __launch_bounds__(256) void k_gemm1(const float* __restrict__ in_feat,
                                               const float* __restrict__ W1,
                                               const float* __restrict__ norm_out,
                                               unsigned char* __restrict__ X1q, int N) {
    __shared__ float Wl[IN_F][H_F];       // 32 KB
    __shared__ float Al[64][IN_F + 4];    // 33 KB
    const int t = threadIdx.x;
    const int base = blockIdx.x * 64;

    for (int i = t; i < IN_F * H_F / 4; i += 256)
        ((float4*)&Wl[0][0])[i] = ((const float4*)W1)[i];
    for (int i = t; i < 64 * IN_F / 4; i += 256) {
        int n = i >> 5;
        int k4 = i & 31;
        int gn = base + n;
        float4 v = make_float4(0.f, 0.f, 0.f, 0.f);
        if (gn < N) v = ((const float4*)(in_feat + (size_t)gn * IN_F))[k4];
        *(float4*)&Al[n][k4 * 4] = v;
    }
    __syncthreads();

    const int c4 = (t & 15) * 4;
    const int r4 = (t >> 4) * 4;
    float acc[4][4] = {};
#pragma unroll 4
    for (int k = 0; k < IN_F; k += 4) {
        float4 w0 = *(const float4*)&Wl[k + 0][c4];
        float4 w1 = *(const float4*)&Wl[k + 1][c4];
        float4 w2 = *(const float4*)&Wl[k + 2][c4];
        float4 w3 = *(const float4*)&Wl[k + 3][c4];
        const float* wp0 = (const float*)&w0;
        const float* wp1 = (const float*)&w1;
        const float* wp2 = (const float*)&w2;
        const float* wp3 = (const float*)&w3;
#pragma unroll
        for (int i = 0; i < 4; ++i) {
            float4 a = *(const float4*)&Al[r4 + i][k];
#pragma unroll
            for (int jj = 0; jj < 4; ++jj)
                acc[i][jj] = fmaf(a.x, wp0[jj],
                             fmaf(a.y, wp1[jj],
                             fmaf(a.z, wp2[jj],
                             fmaf(a.w, wp3[jj], acc[i][jj]))));
        }
    }
#pragma unroll
    for (int i = 0; i < 4; ++i) {
        int n = base + r4 + i;
        if (n < N) {
            float no = norm_out[n];
            int pk = 0;
            pk = __builtin_amdgcn_cvt_pk_fp8_f32(acc[i][0] * no, acc[i][1] * no, pk, false);
            pk = __builtin_amdgcn_cvt_pk_fp8_f32(acc[i][2] * no, acc[i][3] * no, pk, true);
            *(int*)&X1q[(size_t)n * H_F + c4] = pk;
        }
    }
}

// ---- fused aggregation: in-LDS counting sort by dlocal + REGISTER fp8 accumulation ---
// block = bucket (64 nodes); wave w owns nodes [w*16, w*16+16); lane = feature.
__global__ __launch_bounds__(256) void k_agg(const unsigned char* __restrict__ X1q,
                                             const unsigned int* __restrict__ binned,
                                             const int* __restrict__ bucketBase,
                                             const float* __restrict__ norm_in,
                                             const float* __restrict__ norm_out,
                                             const float* __restrict__ wsum,
                                             const float* __restrict__ b1,
                                             float* __restrict__ partials, int N) {
    __shared__ union {
        struct { unsigned cds[CAP]; unsigned cds2[CAP]; } f;   // 16 KB
        float acc[BUCKET * H_F];                               // 16 KB (fallback)
    } u;
    __shared__ int hist[BUCKET];
    __shared__ int cur[BUCKET];
    __shared__ int loff[BUCKET + 1];
    __shared__ float hl[4][64];
    const int tid = threadIdx.x, lane = tid & 63, wave = tid >> 6;
    const int base = bucketBase[blockIdx.x];
    const int cnt  = bucketBase[blockIdx.x + 1] - base;
    const int gbase = blockIdx.x * BUCKET;
    const float bj = b1[lane];
    float hacc = 0.0f;

    if (cnt <= CAP) {
        // ---------- fast path ----------
        if (tid < BUCKET) hist[tid] = 0;
        __syncthreads();
        for (int i = tid; i < cnt; i += 256) {
            unsigned c = binned[base + i];
            u.f.cds[i] = c;
            atomicAdd(&hist[c >> 17], 1);
        }
        __syncthreads();
        if (wave == 0) {
            int v = hist[lane];
            int inc = v;
#pragma unroll
            for (int off = 1; off < 64; off <<= 1) {
                int t2 = __shfl_up(inc, off);
                if (lane >= off) inc += t2;
            }
            loff[lane + 1] = inc;
            cur[lane] = inc - v;          // exclusive prefix
            if (lane == 0) loff[0] = 0;
        }
        __syncthreads();
        for (int i = tid; i < cnt; i += 256) {
            unsigned c = u.f.cds[i];
            int p = atomicAdd(&cur[c >> 17], 1);
            u.f.cds2[p] = c;
        }
        __syncthreads();
        for (int k = 0; k < 16; ++k) {
            int nl = wave * 16 + k;
            int gn = gbase + nl;
            if (gn >= N) break;
            int s0 = loff[nl], s1 = loff[nl + 1];
            float acc = 0.0f;
            int e = s0;
            for (; e + 7 < s1; e += 8) {
                int ss[8]; unsigned qq[8];
#pragma unroll
                for (int v2 = 0; v2 < 8; ++v2)
                    ss[v2] = (int)(u.f.cds2[e + v2] & 0x1FFFFu);
#pragma unroll
                for (int v2 = 0; v2 < 8; ++v2)
                    qq[v2] = X1q[(size_t)ss[v2] * H_F + lane];
#pragma unroll
                for (int v2 = 0; v2 < 8; ++v2)
                    acc += __builtin_amdgcn_cvt_f32_fp8(qq[v2], 0);
            }
            for (; e < s1; ++e) {
                unsigned q = X1q[(size_t)(u.f.cds2[e] & 0x1FFFFu) * H_F + lane];
                acc += __builtin_amdgcn_cvt_f32_fp8(q, 0);
            }
            float v = acc * norm_in[gn] + bj;
            hacc = fmaf(v > 0.0f ? v : 0.0f, norm_out[gn] * wsum[gn], hacc);
        }
    } else {
        // ---------- fallback (cnt > CAP; statistically never for this graph) ----------
        for (int i = tid; i < BUCKET * H_F / 4; i += 256)
            ((float4*)u.acc)[i] = make_float4(0.f, 0.f, 0.f, 0.f);
        __syncthreads();
        for (int e0 = wave * 8; e0 < cnt; e0 += 32) {
            unsigned cc[8];
            float vv[8];
            int dd[8];
#pragma unroll
            for (int v2 = 0; v2 < 8; ++v2) {
                int e = e0 + v2;
                cc[v2] = (e < cnt) ? binned[base + e] : 0u;
            }
#pragma unroll
            for (int v2 = 0; v2 < 8; ++v2) {
                int e = e0 + v2;
                int s = (int)(cc[v2] & 0x1FFFFu);
                dd[v2] = (int)(cc[v2] >> 17);
                vv[v2] = (e < cnt)
                    ? __builtin_amdgcn_cvt_f32_fp8((unsigned)X1q[(size_t)s * H_F + lane], 0)
                    : 0.0f;
            }
#pragma unroll
            for (int v2 = 0; v2 < 8; ++v2)
                atomicAdd(&u.acc[dd[v2] * H_F + lane], vv[v2]);
        }
        __syncthreads();
        for (int k = 0; k < 16; ++k) {
            int nl = wave * 16 + k;
            int gn = gbase + nl;
            if (gn < N) {
                float v = u.acc[nl * H_F + lane] * norm_in[gn] + bj;
                hacc = fmaf(v > 0.0f ? v : 0.0f, norm_out[gn] * wsum[gn], hacc);
            }
        }
    }

    hl[wave][lane] = hacc;
    __syncthreads();
    if (wave == 0)
        partials[(size_t)blockIdx.x * 64 + lane] =
            (hl[0][lane] + hl[1][lane]) + (hl[2][lane] + hl[3][lane]);
}

// ---------------- stage-1 reduction: partials[nb][64] -> red[NRED][64] (f64) ----------
__global__ __launch_bounds__(256) void k_red(const float* __restrict__ partials,
                                             double* __restrict__ red, int nb) {
    const int lane = threadIdx.x & 63, wave = threadIdx.x >> 6;
    const int rpb = (nb + NRED - 1) / NRED;
    const int r0 = blockIdx.x * rpb;
    int r1 = r0 + rpb; if (r1 > nb) r1 = nb;
    double s = 0.0;
    for (int r = r0 + wave; r < r1; r += 4)
        s += (double)partials[(size_t)r * 64 + lane];
    __shared__ double sd[4][64];
    sd[wave][lane] = s;
    __syncthreads();
    if (wave == 0)
        red[(size_t)blockIdx.x * 64 + lane] =
            (sd[0][lane] + sd[1][lane]) + (sd[2][lane] + sd[3][lane]);
}

// ---------------- final: red (f64) -> out = hsum@W2/N + b2 ----------------
__global__ __launch_bounds__(256) void k_final(const double* __restrict__ red,
                                               const float* __restrict__ W2,
                                               const float* __restrict__ b2,
                                               float* __restrict__ out, int N) {
    __shared__ double hs[4][64];
    const int sub = threadIdx.x >> 6;   // 0..3
    const int j   = threadIdx.x & 63;
    double s = 0.0;
    for (int p = sub; p < NRED; p += 4)
        s += red[(size_t)p * 64 + j];
    hs[sub][j] = s;
    __syncthreads();
    if (threadIdx.x < C_F) {
        int c = threadIdx.x;
        double o = 0.0;
        for (int k = 0; k < 64; ++k) {
            double hk = hs[0][k] + hs[1][k] + hs[2][k] + hs[3][k];
            o += hk * (double)W2[k * C_F + c];
        }
        out[c] = (float)(o / (double)N + (double)b2[c]);
    }
}

extern "C" void kernel_launch(void* const* d_in, const int* in_sizes, int n_in,
                              void* d_out, int out_size, void* d_ws, size_t ws_size,
                              hipStream_t stream) {
    const float* in_feat = (const float*)d_in[0];
    const int*   src     = (const int*)d_in[1];
    const int*   dst     = (const int*)d_in[2];
    const float* W1      = (const float*)d_in[3];
    const float* b1      = (const float*)d_in[4];
    const float* W2      = (const float*)d_in[5];
    const float* b2      = (const float*)d_in[6];
    float* out = (float*)d_out;

    const int N = in_sizes[0] / IN_F;           // 100000
    const int E = in_sizes[1];                  // 1600000
    const int nb = (N + BUCKET - 1) / BUCKET;   // 1563 (<= MAXB)
    const int nBin = (E + EPB - 1) / EPB;       // 196 (k_bhist)
    const int nBinW = (E + EPB2 - 1) / EPB2;    // 49  (k_bin, per role)

    // ---- workspace layout (4B units) ----
    unsigned int* binnedD = (unsigned int*)d_ws;         // E
    unsigned int* binnedS = binnedD + E;                 // E
    int*   cntD   = (int*)(binnedS + E);                 // MAXB  \ zeroed
    int*   cntS   = cntD + MAXB;                         // MAXB  /
    int*   baseD  = cntS + MAXB;                         // MAXB+1
    int*   curD   = baseD + MAXB + 1;                    // MAXB
    int*   baseS  = curD + MAXB;                         // MAXB+1
    int*   curS   = baseS + MAXB + 1;                    // MAXB
    float* norm_in  = (float*)(curS + MAXB);             // N
    float* norm_out = norm_in + N;                       // N
    float* wsum     = norm_out + N;                      // N
    unsigned char* X1q = (unsigned char*)(wsum + N);     // 64N bytes
    float* partials = (float*)(X1q + 64 * (size_t)N);    // nb*64
    double* red     = (double*)(partials + (size_t)nb * 64);  // NRED*64 f64

    // only the bucket-count accumulators are read-before-write
    hipMemsetAsync(cntD, 0, 2 * MAXB * sizeof(int), stream);

    k_bhist<<<nBin, 256, 0, stream>>>(src, dst, cntS, cntD, E, nb);

    k_bucketscan2<<<1, 1024, 0, stream>>>(cntD, cntS, baseD, curD, baseS, curS, nb, E);

    k_bin<<<2 * nBinW, 512, 0, stream>>>(src, dst, curD, curS, binnedD, binnedS,
                                         E, nb, nBinW);

    k_normin<<<nb, 256, 0, stream>>>(binnedD, baseD, norm_in, N);
    k_wsum  <<<nb, 256, 0, stream>>>(binnedS, baseS, norm_in, wsum, norm_out, N);

    k_gemm1<<<(N + 63) / 64, 256, 0, stream>>>(in_feat, W1, norm_out, X1q, N);

    k_agg<<<nb, 256, 0, stream>>>(X1q, binnedD, baseD, norm_in, norm_out,
                                  wsum, b1, partials, N);

    k_red  <<<NRED, 256, 0, stream>>>(partials, red, nb);
    k_final<<<1, 256, 0, stream>>>(red, W2, b2, out, N);
}